// Round 4
// baseline (144.204 us; speedup 1.0000x reference)
//
#include <hip/hip_runtime.h>
#include <hip/hip_cooperative_groups.h>
#include <hip/hip_bf16.h>
#include <math.h>

namespace cg = cooperative_groups;

#define SEQ 2048
#define DM 256
#define NH 8
#define DH 32

typedef unsigned short ushort_t;
typedef __attribute__((ext_vector_type(8))) unsigned short u16x8;
typedef __attribute__((ext_vector_type(8))) __bf16 b16x8;
typedef __attribute__((ext_vector_type(4))) float f32x4;

static __device__ __forceinline__ b16x8 as_b(u16x8 v) {
    union { u16x8 u; b16x8 b; } x; x.u = v; return x.b;
}
// RTN-even f32 -> bf16 bits
static __device__ __forceinline__ ushort_t f2bh(float f) {
    unsigned u = __float_as_uint(f);
    return (ushort_t)((u + 0x7fffu + ((u >> 16) & 1u)) >> 16);
}

// ================= P0: convert x,[Wq;Wk],Wo -> bf16 (grid-strided, 256 blocks) =================
static __device__ __forceinline__ void phase_convert(
    int B, const float* __restrict__ x, const float* __restrict__ Wq,
    const float* __restrict__ Wk, const float* __restrict__ Wo,
    ushort_t* __restrict__ Xbf, ushort_t* __restrict__ W2bf, ushort_t* __restrict__ Wobf)
{
    // 524288 + 131072 + 65536 = 720896 elems = 90112 vec8 over 65536 threads
    #pragma unroll
    for (int it = 0; it < 2; ++it) {
        int idx = it * 65536 + B * 256 + (int)threadIdx.x;
        if (idx < 90112) {
            int e = idx * 8;
            const float* src;
            ushort_t* dst;
            if (e < 524288) { src = x + e; dst = Xbf + e; }
            else if (e < 655360) {
                int o = e - 524288;
                src = (o < 65536) ? (Wq + o) : (Wk + (o - 65536));
                dst = W2bf + o;
            } else {
                int o = e - 655360;
                src = Wo + o; dst = Wobf + o;
            }
            float4 a = ((const float4*)src)[0];
            float4 b = ((const float4*)src)[1];
            u16x8 r;
            r[0] = f2bh(a.x); r[1] = f2bh(a.y); r[2] = f2bh(a.z); r[3] = f2bh(a.w);
            r[4] = f2bh(b.x); r[5] = f2bh(b.y); r[6] = f2bh(b.z); r[7] = f2bh(b.w);
            *(u16x8*)dst = r;
        }
    }
}

// ================= P1: proj2 MFMA + fused RoPE =================
// mb in 0..31, nb in 0..7. nb<4: Q-path (rope -> Qrot, Vt scatter, psum); nb>=4: Kbf.
static __device__ __forceinline__ void phase_proj2rope(
    int mb, int nb, const ushort_t* __restrict__ Xbf, const ushort_t* __restrict__ W2bf,
    ushort_t* __restrict__ Qrot, ushort_t* __restrict__ Kbf, ushort_t* __restrict__ Vt,
    float* __restrict__ psum)
{
    const int t = (int)threadIdx.x;
    const int w = t >> 6, l = t & 63, g = l >> 4, ln = l & 15;
    const int row0 = mb * 64 + w * 16;
    const int col0 = nb * 64;

    u16x8 af[8];
    const ushort_t* ap = Xbf + (row0 + ln) * DM + g * 8;
    #pragma unroll
    for (int kk = 0; kk < 8; ++kk) af[kk] = *(const u16x8*)(ap + kk * 32);

    f32x4 acc[4] = {{0,0,0,0},{0,0,0,0},{0,0,0,0},{0,0,0,0}};
    #pragma unroll
    for (int kk = 0; kk < 8; ++kk) {
        #pragma unroll
        for (int nf = 0; nf < 4; ++nf) {
            u16x8 bfv = *(const u16x8*)(W2bf + (col0 + nf * 16 + ln) * DM + g * 8 + kk * 32);
            acc[nf] = __builtin_amdgcn_mfma_f32_16x16x32_bf16(as_b(af[kk]), as_b(bfv), acc[nf], 0, 0, 0);
        }
    }

    if (nb < 4) {
        #pragma unroll
        for (int nf = 0; nf < 4; ++nf) {
            const int col = col0 + nf * 16 + ln;
            const int ch = col >> 1;
            const float inv = exp2f(-(float)ch * 0.10381025296522976f); // 10000^(-2c/256)
            const bool odd = (col & 1);
            #pragma unroll
            for (int r = 0; r < 4; ++r) {
                const int row = row0 + 4 * g + r;
                float v = acc[nf][r];
                // Vt scatter (V = XQ pre-rope; pi-permuted for PV fragment layout)
                int kl = row & 31;
                int pos = ((kl >> 2) & 3) * 8 + ((kl >> 4) & 1) * 4 + (kl & 3);
                Vt[col * SEQ + (row & ~31) + pos] = f2bh(v);
                // rope: partner value at col^1 lives in lane l^1
                float other = __shfl_xor(v, 1, 64);
                float ang = (float)row * inv;
                float sn, cs;
                sincosf(ang, &sn, &cs);
                float xe = odd ? other : v;
                float xo = odd ? v : other;
                float o = odd ? (xe * sn + xo * cs) : (xe * cs - xo * sn);
                Qrot[row * DM + col] = f2bh(o);
            }
            float s = acc[nf][0] + acc[nf][1] + acc[nf][2] + acc[nf][3];
            s += __shfl_xor(s, 16, 64);
            s += __shfl_xor(s, 32, 64);
            if (g == 0) psum[(mb * 4 + w) * DM + col] = s;
        }
    } else {
        #pragma unroll
        for (int nf = 0; nf < 4; ++nf) {
            const int col = col0 - 256 + nf * 16 + ln;
            #pragma unroll
            for (int r = 0; r < 4; ++r)
                Kbf[(row0 + 4 * g + r) * DM + col] = f2bh(acc[nf][r]);
        }
    }
}

// ================= P2: attention (anti-causal), 4 units/block, 4-way k-split =================
static __device__ __forceinline__ void phase_attn(
    int bb, int h, const int* __restrict__ tp, const ushort_t* __restrict__ Qrot,
    const ushort_t* __restrict__ Kbf, const ushort_t* __restrict__ Vt,
    const float* __restrict__ psum, ushort_t* __restrict__ AObf)
{
    __shared__ float sm[4][64], sl[4][64], sacc[4][64][8];
    __shared__ float fixred[256];

    const int t = (int)threadIdx.x;
    const int w = t >> 6, l = t & 63, g = l >> 4, ln = l & 15;
    const ushort_t* Kh = Kbf + h * DH;
    const ushort_t* Vh = Vt + (h * DH) * SEQ;

    if (bb == 0) {
        // row 2047 = column mean of V (fully-masked softmax), this head's 32 cols
        const int c32 = t & 31, seg = t >> 5;
        float partial = 0.f;
        #pragma unroll
        for (int r = 0; r < 16; ++r) partial += psum[(seg * 16 + r) * DM + h * 32 + c32];
        fixred[t] = partial;
        __syncthreads();
        if (t < 32) {
            float s = 0.f;
            #pragma unroll
            for (int sg = 0; sg < 8; ++sg) s += fixred[sg * 32 + t];
            AObf[2047 * DM + h * 32 + t] = f2bh(s * (1.0f / 2048.0f));
        }
    }

    const int qts[4] = {bb, 63 - bb, 64 + bb, 127 - bb};
    for (int ui = 0; ui < 4; ++ui) {
        const int qt16 = qts[ui];
        const int qrow = qt16 * 16 + ln;
        const int pg = tp[qrow];
        const u16x8 qf = *(const u16x8*)(Qrot + pg * DM + h * DH + g * 8);
        const int lo = qt16 >> 2;
        const int n = 32 - lo;
        const int ks = lo + (w * n) / 4;
        const int ke = lo + ((w + 1) * n) / 4;

        float m = -INFINITY, lsum = 0.f;
        f32x4 acc0 = {0,0,0,0}, acc1 = {0,0,0,0};

        if (ks < ke) {
            u16x8 ka[4], va[4], kn[4], vn[4];
            #pragma unroll
            for (int st = 0; st < 4; ++st)
                ka[st] = *(const u16x8*)(Kh + (ks * 64 + st * 16 + ln) * DM + g * 8);
            #pragma unroll
            for (int c = 0; c < 2; ++c)
                #pragma unroll
                for (int df = 0; df < 2; ++df)
                    va[c * 2 + df] = *(const u16x8*)(Vh + (df * 16 + ln) * SEQ + ks * 64 + c * 32 + g * 8);

            for (int kt = ks; kt < ke; ++kt) {
                if (kt + 1 < ke) {
                    #pragma unroll
                    for (int st = 0; st < 4; ++st)
                        kn[st] = *(const u16x8*)(Kh + ((kt + 1) * 64 + st * 16 + ln) * DM + g * 8);
                    #pragma unroll
                    for (int c = 0; c < 2; ++c)
                        #pragma unroll
                        for (int df = 0; df < 2; ++df)
                            vn[c * 2 + df] = *(const u16x8*)(Vh + (df * 16 + ln) * SEQ + (kt + 1) * 64 + c * 32 + g * 8);
                }

                f32x4 s[4];
                #pragma unroll
                for (int st = 0; st < 4; ++st) {
                    f32x4 z = {0,0,0,0};
                    s[st] = __builtin_amdgcn_mfma_f32_16x16x32_bf16(as_b(ka[st]), as_b(qf), z, 0, 0, 0);
                }

                float sv[16];
                float tmax = -INFINITY;
                #pragma unroll
                for (int st = 0; st < 4; ++st)
                    #pragma unroll
                    for (int r = 0; r < 4; ++r) {
                        int kg = kt * 64 + st * 16 + g * 4 + r;
                        float v = s[st][r] * 0.17677669529663687f; // 1/sqrt(32)
                        v = (kg > qrow) ? v : -1.0e9f;             // anti-causal mask
                        sv[st * 4 + r] = v;
                        tmax = fmaxf(tmax, v);
                    }
                tmax = fmaxf(tmax, __shfl_xor(tmax, 16, 64));
                tmax = fmaxf(tmax, __shfl_xor(tmax, 32, 64));

                float mn = fmaxf(m, tmax);
                float corr = __expf(m - mn);
                m = mn;

                float ts = 0.f;
                ushort_t pb[16];
                #pragma unroll
                for (int i = 0; i < 16; ++i) {
                    float e = __expf(sv[i] - m);
                    ts += e;
                    pb[i] = f2bh(e);
                }
                ts += __shfl_xor(ts, 16, 64);
                ts += __shfl_xor(ts, 32, 64);
                lsum = lsum * corr + ts;
                #pragma unroll
                for (int i = 0; i < 4; ++i) { acc0[i] *= corr; acc1[i] *= corr; }

                #pragma unroll
                for (int c = 0; c < 2; ++c) {
                    u16x8 pf;
                    #pragma unroll
                    for (int r = 0; r < 4; ++r) { pf[r] = pb[(2 * c) * 4 + r]; pf[4 + r] = pb[(2 * c + 1) * 4 + r]; }
                    acc0 = __builtin_amdgcn_mfma_f32_16x16x32_bf16(as_b(va[c * 2 + 0]), as_b(pf), acc0, 0, 0, 0);
                    acc1 = __builtin_amdgcn_mfma_f32_16x16x32_bf16(as_b(va[c * 2 + 1]), as_b(pf), acc1, 0, 0, 0);
                }

                if (kt + 1 < ke) {
                    #pragma unroll
                    for (int i = 0; i < 4; ++i) { ka[i] = kn[i]; va[i] = vn[i]; }
                }
            }
        }

        sm[w][l] = m;
        sl[w][l] = lsum;
        #pragma unroll
        for (int r = 0; r < 4; ++r) { sacc[w][l][r] = acc0[r]; sacc[w][l][4 + r] = acc1[r]; }
        __syncthreads();

        if (w == 0 && qrow != 2047) {
            float m2 = fmaxf(fmaxf(sm[0][l], sm[1][l]), fmaxf(sm[2][l], sm[3][l]));
            float cw0 = __expf(sm[0][l] - m2), cw1 = __expf(sm[1][l] - m2);
            float cw2 = __expf(sm[2][l] - m2), cw3 = __expf(sm[3][l] - m2);
            float L = sl[0][l] * cw0 + sl[1][l] * cw1 + sl[2][l] * cw2 + sl[3][l] * cw3;
            float invL = 1.0f / L;
            ushort_t* o = AObf + qrow * DM + h * DH;
            #pragma unroll
            for (int r = 0; r < 4; ++r) {
                float o0 = (sacc[0][l][r] * cw0 + sacc[1][l][r] * cw1 +
                            sacc[2][l][r] * cw2 + sacc[3][l][r] * cw3) * invL;
                float o1 = (sacc[0][l][4 + r] * cw0 + sacc[1][l][4 + r] * cw1 +
                            sacc[2][l][4 + r] * cw2 + sacc[3][l][4 + r] * cw3) * invL;
                o[4 * g + r]      = f2bh(o0);
                o[16 + 4 * g + r] = f2bh(o1);
            }
        }
        __syncthreads();
    }
}

// ================= P3: proj1 MFMA: out = AObf * Wobf^T (f32) =================
static __device__ __forceinline__ void phase_proj1(
    int mb, int nb, const ushort_t* __restrict__ AObf, const ushort_t* __restrict__ Wobf,
    float* __restrict__ out)
{
    const int t = (int)threadIdx.x;
    const int w = t >> 6, l = t & 63, g = l >> 4, ln = l & 15;
    const int row0 = mb * 64 + w * 16;
    const int col0 = nb * 32;

    u16x8 af[8];
    const ushort_t* ap = AObf + (row0 + ln) * DM + g * 8;
    #pragma unroll
    for (int kk = 0; kk < 8; ++kk) af[kk] = *(const u16x8*)(ap + kk * 32);

    f32x4 acc[2] = {{0,0,0,0},{0,0,0,0}};
    #pragma unroll
    for (int kk = 0; kk < 8; ++kk) {
        #pragma unroll
        for (int nf = 0; nf < 2; ++nf) {
            u16x8 bfv = *(const u16x8*)(Wobf + (col0 + nf * 16 + ln) * DM + g * 8 + kk * 32);
            acc[nf] = __builtin_amdgcn_mfma_f32_16x16x32_bf16(as_b(af[kk]), as_b(bfv), acc[nf], 0, 0, 0);
        }
    }
    #pragma unroll
    for (int nf = 0; nf < 2; ++nf) {
        const int col = col0 + nf * 16 + ln;
        #pragma unroll
        for (int r = 0; r < 4; ++r)
            out[(row0 + 4 * g + r) * DM + col] = acc[nf][r];
    }
}

// ================= mega kernel (cooperative) =================
__global__ __launch_bounds__(256) void mega_kernel(
    const float* __restrict__ x, const int* __restrict__ tp,
    const float* __restrict__ Wq, const float* __restrict__ Wk, const float* __restrict__ Wo,
    float* __restrict__ out, float* __restrict__ psum,
    ushort_t* __restrict__ Xbf, ushort_t* __restrict__ W2bf, ushort_t* __restrict__ Wobf,
    ushort_t* __restrict__ Qrot, ushort_t* __restrict__ Kbf, ushort_t* __restrict__ Vt,
    ushort_t* __restrict__ AObf)
{
    cg::grid_group grid = cg::this_grid();
    const int B = (int)blockIdx.x;

    phase_convert(B, x, Wq, Wk, Wo, Xbf, W2bf, Wobf);
    grid.sync();
    phase_proj2rope(B >> 3, B & 7, Xbf, W2bf, Qrot, Kbf, Vt, psum);
    grid.sync();
    phase_attn(B >> 3, B & 7, tp, Qrot, Kbf, Vt, psum, AObf);
    grid.sync();
    phase_proj1(B >> 3, B & 7, AObf, Wobf, out);
}

// ================= fallback (non-cooperative) wrappers =================
__global__ __launch_bounds__(256) void k_convert(
    const float* __restrict__ x, const float* __restrict__ Wq, const float* __restrict__ Wk,
    const float* __restrict__ Wo, ushort_t* __restrict__ Xbf, ushort_t* __restrict__ W2bf,
    ushort_t* __restrict__ Wobf)
{ phase_convert((int)blockIdx.x, x, Wq, Wk, Wo, Xbf, W2bf, Wobf); }

__global__ __launch_bounds__(256) void k_proj2rope(
    const ushort_t* __restrict__ Xbf, const ushort_t* __restrict__ W2bf,
    ushort_t* __restrict__ Qrot, ushort_t* __restrict__ Kbf, ushort_t* __restrict__ Vt,
    float* __restrict__ psum)
{ phase_proj2rope((int)blockIdx.x, (int)blockIdx.y, Xbf, W2bf, Qrot, Kbf, Vt, psum); }

__global__ __launch_bounds__(256) void k_attn(
    const int* __restrict__ tp, const ushort_t* __restrict__ Qrot,
    const ushort_t* __restrict__ Kbf, const ushort_t* __restrict__ Vt,
    const float* __restrict__ psum, ushort_t* __restrict__ AObf)
{ phase_attn((int)blockIdx.x, (int)blockIdx.y, tp, Qrot, Kbf, Vt, psum, AObf); }

__global__ __launch_bounds__(256) void k_proj1(
    const ushort_t* __restrict__ AObf, const ushort_t* __restrict__ Wobf,
    float* __restrict__ out)
{ phase_proj1((int)blockIdx.x, (int)blockIdx.y, AObf, Wobf, out); }

extern "C" void kernel_launch(void* const* d_in, const int* in_sizes, int n_in,
                              void* d_out, int out_size, void* d_ws, size_t ws_size,
                              hipStream_t stream) {
    const float* x  = (const float*)d_in[0];
    const int*   tp = (const int*)d_in[1];
    const float* Wq = (const float*)d_in[2];
    const float* Wk = (const float*)d_in[3];
    // d_in[4] = v_weight — UNUSED (reference computes x_v with q_weight)
    const float* Wo = (const float*)d_in[5];
    float* out = (float*)d_out;

    float* ws = (float*)d_ws;
    float*    psum = ws;                          // 128*256 f32
    ushort_t* Xbf  = (ushort_t*)(ws + 32768);     // 2048*256 bf16
    ushort_t* W2bf = (ushort_t*)(ws + 294912);    // 512*256 bf16 ([Wq;Wk])
    ushort_t* Wobf = (ushort_t*)(ws + 360448);    // 256*256 bf16
    ushort_t* Qrot = (ushort_t*)(ws + 393216);    // 2048*256 bf16 (rotated, pre-gather)
    ushort_t* Kbf  = (ushort_t*)(ws + 655360);    // 2048*256 bf16
    ushort_t* Vt   = (ushort_t*)(ws + 917504);    // [256][2048] bf16, pi-permuted
    ushort_t* AObf = (ushort_t*)(ws + 1179648);   // 2048*256 bf16

    void* args[] = { (void*)&x, (void*)&tp, (void*)&Wq, (void*)&Wk, (void*)&Wo,
                     (void*)&out, (void*)&psum, (void*)&Xbf, (void*)&W2bf, (void*)&Wobf,
                     (void*)&Qrot, (void*)&Kbf, (void*)&Vt, (void*)&AObf };

    hipError_t err = hipLaunchCooperativeKernel((const void*)mega_kernel,
                                                dim3(256), dim3(256), args, 0, stream);
    if (err != hipSuccess) {
        (void)hipGetLastError(); // clear sticky error, fall back to plain launches
        k_convert<<<256, 256, 0, stream>>>(x, Wq, Wk, Wo, Xbf, W2bf, Wobf);
        k_proj2rope<<<dim3(32, 8), 256, 0, stream>>>(Xbf, W2bf, Qrot, Kbf, Vt, psum);
        k_attn<<<dim3(32, 8), 256, 0, stream>>>(tp, Qrot, Kbf, Vt, psum, AObf);
        k_proj1<<<dim3(32, 8), 256, 0, stream>>>(AObf, Wobf, out);
    }
}

// Round 5
// 46.065 us; speedup vs baseline: 3.1304x; 3.1304x over previous
//
#include <hip/hip_runtime.h>
#include <hip/hip_bf16.h>
#include <math.h>

#define SEQ 2048
#define DM 256
#define NH 8
#define DH 32

typedef unsigned short ushort_t;
typedef __attribute__((ext_vector_type(8))) unsigned short u16x8;
typedef __attribute__((ext_vector_type(8))) __bf16 b16x8;
typedef __attribute__((ext_vector_type(4))) float f32x4;

static __device__ __forceinline__ b16x8 as_b(u16x8 v) {
    union { u16x8 u; b16x8 b; } x; x.u = v; return x.b;
}
// RTN-even f32 -> bf16 bits
static __device__ __forceinline__ ushort_t f2bh(float f) {
    unsigned u = __float_as_uint(f);
    return (ushort_t)((u + 0x7fffu + ((u >> 16) & 1u)) >> 16);
}
// load 8 f32, convert to bf16 fragment half
static __device__ __forceinline__ u16x8 ld8_f2b(const float* __restrict__ p) {
    float4 a = ((const float4*)p)[0];
    float4 b = ((const float4*)p)[1];
    u16x8 r;
    r[0] = f2bh(a.x); r[1] = f2bh(a.y); r[2] = f2bh(a.z); r[3] = f2bh(a.w);
    r[4] = f2bh(b.x); r[5] = f2bh(b.y); r[6] = f2bh(b.z); r[7] = f2bh(b.w);
    return r;
}

// ================= K1: proj2 MFMA (f32 in, convert in-register) + fused RoPE =================
// grid (32 mb, 8 nb), 256 thr. nb<4: Q-path (rope -> Qrot, Vt scatter, psum); nb>=4: Kbf.
__global__ __launch_bounds__(256) void k_proj2rope(
    const float* __restrict__ x, const float* __restrict__ Wq, const float* __restrict__ Wk,
    ushort_t* __restrict__ Qrot, ushort_t* __restrict__ Kbf, ushort_t* __restrict__ Vt,
    float* __restrict__ psum)
{
    const int t = (int)threadIdx.x;
    const int w = t >> 6, l = t & 63, g = l >> 4, ln = l & 15;
    const int mb = (int)blockIdx.x, nb = (int)blockIdx.y;
    const int row0 = mb * 64 + w * 16;
    const int col0 = nb * 64;
    const float* Wsrc = (nb < 4) ? (Wq + col0 * DM) : (Wk + (col0 - 256) * DM);

    u16x8 af[8];
    const float* ap = x + (row0 + ln) * DM + g * 8;
    #pragma unroll
    for (int kk = 0; kk < 8; ++kk) af[kk] = ld8_f2b(ap + kk * 32);

    f32x4 acc[4] = {{0,0,0,0},{0,0,0,0},{0,0,0,0},{0,0,0,0}};
    #pragma unroll
    for (int kk = 0; kk < 8; ++kk) {
        #pragma unroll
        for (int nf = 0; nf < 4; ++nf) {
            u16x8 bfv = ld8_f2b(Wsrc + (nf * 16 + ln) * DM + g * 8 + kk * 32);
            acc[nf] = __builtin_amdgcn_mfma_f32_16x16x32_bf16(as_b(af[kk]), as_b(bfv), acc[nf], 0, 0, 0);
        }
    }

    if (nb < 4) {
        #pragma unroll
        for (int nf = 0; nf < 4; ++nf) {
            const int col = col0 + nf * 16 + ln;
            const int ch = col >> 1;
            const float inv = exp2f(-(float)ch * 0.10381025296522976f); // 10000^(-2c/256)
            const bool odd = (col & 1);
            #pragma unroll
            for (int r = 0; r < 4; ++r) {
                const int row = row0 + 4 * g + r;
                float v = acc[nf][r];
                // Vt scatter (V = x*Wq^T pre-rope; pi-permuted for PV fragment layout)
                int kl = row & 31;
                int pos = ((kl >> 2) & 3) * 8 + ((kl >> 4) & 1) * 4 + (kl & 3);
                Vt[col * SEQ + (row & ~31) + pos] = f2bh(v);
                // rope: partner value at col^1 lives in lane l^1
                float other = __shfl_xor(v, 1, 64);
                float ang = (float)row * inv;
                float sn, cs;
                sincosf(ang, &sn, &cs);
                float xe = odd ? other : v;
                float xo = odd ? v : other;
                float o = odd ? (xe * sn + xo * cs) : (xe * cs - xo * sn);
                Qrot[row * DM + col] = f2bh(o);
            }
            float s = acc[nf][0] + acc[nf][1] + acc[nf][2] + acc[nf][3];
            s += __shfl_xor(s, 16, 64);
            s += __shfl_xor(s, 32, 64);
            if (g == 0) psum[(mb * 4 + w) * DM + col] = s;
        }
    } else {
        #pragma unroll
        for (int nf = 0; nf < 4; ++nf) {
            const int col = col0 - 256 + nf * 16 + ln;
            #pragma unroll
            for (int r = 0; r < 4; ++r)
                Kbf[(row0 + 4 * g + r) * DM + col] = f2bh(acc[nf][r]);
        }
    }
}

// ================= K2: attention (anti-causal), grid (64,8), 2 units/block, 4-way k-split =================
__global__ __launch_bounds__(256) void k_attn(
    const int* __restrict__ tp, const ushort_t* __restrict__ Qrot,
    const ushort_t* __restrict__ Kbf, const ushort_t* __restrict__ Vt,
    const float* __restrict__ psum, ushort_t* __restrict__ AObf)
{
    __shared__ float sm[4][64], sl[4][64], sacc[4][64][8];
    __shared__ float fixred[256];

    const int t = (int)threadIdx.x;
    const int w = t >> 6, l = t & 63, g = l >> 4, ln = l & 15;
    const int bb = (int)blockIdx.x, h = (int)blockIdx.y;
    const ushort_t* Kh = Kbf + h * DH;
    const ushort_t* Vh = Vt + (h * DH) * SEQ;

    if (bb == 0) {
        // row 2047 = column mean of V (fully-masked softmax), this head's 32 cols
        const int c32 = t & 31, seg = t >> 5;
        float partial = 0.f;
        #pragma unroll
        for (int r = 0; r < 16; ++r) partial += psum[(seg * 16 + r) * DM + h * 32 + c32];
        fixred[t] = partial;
        __syncthreads();
        if (t < 32) {
            float s = 0.f;
            #pragma unroll
            for (int sg = 0; sg < 8; ++sg) s += fixred[sg * 32 + t];
            AObf[2047 * DM + h * 32 + t] = f2bh(s * (1.0f / 2048.0f));
        }
    }

    const int qts[2] = {bb, 127 - bb};
    #pragma unroll
    for (int ui = 0; ui < 2; ++ui) {
        const int qt16 = qts[ui];
        const int qrow = qt16 * 16 + ln;
        const int pg = tp[qrow];
        const u16x8 qf = *(const u16x8*)(Qrot + pg * DM + h * DH + g * 8);
        const int lo = qt16 >> 2;
        const int n = 32 - lo;
        const int ks = lo + (w * n) / 4;
        const int ke = lo + ((w + 1) * n) / 4;

        float m = -INFINITY, lsum = 0.f;
        f32x4 acc0 = {0,0,0,0}, acc1 = {0,0,0,0};

        if (ks < ke) {
            u16x8 ka[4], va[4], kn[4], vn[4];
            #pragma unroll
            for (int st = 0; st < 4; ++st)
                ka[st] = *(const u16x8*)(Kh + (ks * 64 + st * 16 + ln) * DM + g * 8);
            #pragma unroll
            for (int c = 0; c < 2; ++c)
                #pragma unroll
                for (int df = 0; df < 2; ++df)
                    va[c * 2 + df] = *(const u16x8*)(Vh + (df * 16 + ln) * SEQ + ks * 64 + c * 32 + g * 8);

            for (int kt = ks; kt < ke; ++kt) {
                if (kt + 1 < ke) {
                    #pragma unroll
                    for (int st = 0; st < 4; ++st)
                        kn[st] = *(const u16x8*)(Kh + ((kt + 1) * 64 + st * 16 + ln) * DM + g * 8);
                    #pragma unroll
                    for (int c = 0; c < 2; ++c)
                        #pragma unroll
                        for (int df = 0; df < 2; ++df)
                            vn[c * 2 + df] = *(const u16x8*)(Vh + (df * 16 + ln) * SEQ + (kt + 1) * 64 + c * 32 + g * 8);
                }

                f32x4 s[4];
                #pragma unroll
                for (int st = 0; st < 4; ++st) {
                    f32x4 z = {0,0,0,0};
                    s[st] = __builtin_amdgcn_mfma_f32_16x16x32_bf16(as_b(ka[st]), as_b(qf), z, 0, 0, 0);
                }

                float sv[16];
                float tmax = -INFINITY;
                #pragma unroll
                for (int st = 0; st < 4; ++st)
                    #pragma unroll
                    for (int r = 0; r < 4; ++r) {
                        int kg = kt * 64 + st * 16 + g * 4 + r;
                        float v = s[st][r] * 0.17677669529663687f; // 1/sqrt(32)
                        v = (kg > qrow) ? v : -1.0e9f;             // anti-causal mask
                        sv[st * 4 + r] = v;
                        tmax = fmaxf(tmax, v);
                    }
                tmax = fmaxf(tmax, __shfl_xor(tmax, 16, 64));
                tmax = fmaxf(tmax, __shfl_xor(tmax, 32, 64));

                float mn = fmaxf(m, tmax);
                float corr = __expf(m - mn);
                m = mn;

                float ts = 0.f;
                ushort_t pb[16];
                #pragma unroll
                for (int i = 0; i < 16; ++i) {
                    float e = __expf(sv[i] - m);
                    ts += e;
                    pb[i] = f2bh(e);
                }
                ts += __shfl_xor(ts, 16, 64);
                ts += __shfl_xor(ts, 32, 64);
                lsum = lsum * corr + ts;
                #pragma unroll
                for (int i = 0; i < 4; ++i) { acc0[i] *= corr; acc1[i] *= corr; }

                #pragma unroll
                for (int c = 0; c < 2; ++c) {
                    u16x8 pf;
                    #pragma unroll
                    for (int r = 0; r < 4; ++r) { pf[r] = pb[(2 * c) * 4 + r]; pf[4 + r] = pb[(2 * c + 1) * 4 + r]; }
                    acc0 = __builtin_amdgcn_mfma_f32_16x16x32_bf16(as_b(va[c * 2 + 0]), as_b(pf), acc0, 0, 0, 0);
                    acc1 = __builtin_amdgcn_mfma_f32_16x16x32_bf16(as_b(va[c * 2 + 1]), as_b(pf), acc1, 0, 0, 0);
                }

                if (kt + 1 < ke) {
                    #pragma unroll
                    for (int i = 0; i < 4; ++i) { ka[i] = kn[i]; va[i] = vn[i]; }
                }
            }
        }

        sm[w][l] = m;
        sl[w][l] = lsum;
        #pragma unroll
        for (int r = 0; r < 4; ++r) { sacc[w][l][r] = acc0[r]; sacc[w][l][4 + r] = acc1[r]; }
        __syncthreads();

        if (w == 0 && qrow != 2047) {
            float m2 = fmaxf(fmaxf(sm[0][l], sm[1][l]), fmaxf(sm[2][l], sm[3][l]));
            float cw0 = __expf(sm[0][l] - m2), cw1 = __expf(sm[1][l] - m2);
            float cw2 = __expf(sm[2][l] - m2), cw3 = __expf(sm[3][l] - m2);
            float L = sl[0][l] * cw0 + sl[1][l] * cw1 + sl[2][l] * cw2 + sl[3][l] * cw3;
            float invL = 1.0f / L;
            ushort_t* o = AObf + qrow * DM + h * DH;
            #pragma unroll
            for (int r = 0; r < 4; ++r) {
                float o0 = (sacc[0][l][r] * cw0 + sacc[1][l][r] * cw1 +
                            sacc[2][l][r] * cw2 + sacc[3][l][r] * cw3) * invL;
                float o1 = (sacc[0][l][4 + r] * cw0 + sacc[1][l][4 + r] * cw1 +
                            sacc[2][l][4 + r] * cw2 + sacc[3][l][4 + r] * cw3) * invL;
                o[4 * g + r]      = f2bh(o0);
                o[16 + 4 * g + r] = f2bh(o1);
            }
        }
        __syncthreads();
    }
}

// ================= K3: proj1 MFMA: out = AObf * Wo^T (f32 in-register convert, f32 out) =================
__global__ __launch_bounds__(256) void k_proj1(
    const ushort_t* __restrict__ AObf, const float* __restrict__ Wo,
    float* __restrict__ out)
{
    const int t = (int)threadIdx.x;
    const int w = t >> 6, l = t & 63, g = l >> 4, ln = l & 15;
    const int mb = (int)blockIdx.x, nb = (int)blockIdx.y;
    const int row0 = mb * 64 + w * 16;
    const int col0 = nb * 32;

    u16x8 af[8];
    const ushort_t* ap = AObf + (row0 + ln) * DM + g * 8;
    #pragma unroll
    for (int kk = 0; kk < 8; ++kk) af[kk] = *(const u16x8*)(ap + kk * 32);

    f32x4 acc[2] = {{0,0,0,0},{0,0,0,0}};
    #pragma unroll
    for (int kk = 0; kk < 8; ++kk) {
        #pragma unroll
        for (int nf = 0; nf < 2; ++nf) {
            u16x8 bfv = ld8_f2b(Wo + (col0 + nf * 16 + ln) * DM + g * 8 + kk * 32);
            acc[nf] = __builtin_amdgcn_mfma_f32_16x16x32_bf16(as_b(af[kk]), as_b(bfv), acc[nf], 0, 0, 0);
        }
    }
    #pragma unroll
    for (int nf = 0; nf < 2; ++nf) {
        const int col = col0 + nf * 16 + ln;
        #pragma unroll
        for (int r = 0; r < 4; ++r)
            out[(row0 + 4 * g + r) * DM + col] = acc[nf][r];
    }
}

extern "C" void kernel_launch(void* const* d_in, const int* in_sizes, int n_in,
                              void* d_out, int out_size, void* d_ws, size_t ws_size,
                              hipStream_t stream) {
    const float* x  = (const float*)d_in[0];
    const int*   tp = (const int*)d_in[1];
    const float* Wq = (const float*)d_in[2];
    const float* Wk = (const float*)d_in[3];
    // d_in[4] = v_weight — UNUSED (reference computes x_v with q_weight)
    const float* Wo = (const float*)d_in[5];
    float* out = (float*)d_out;

    float* ws = (float*)d_ws;
    float*    psum = ws;                          // 128*256 f32
    ushort_t* Qrot = (ushort_t*)(ws + 32768);     // 2048*256 bf16 (rotated, pre-gather)
    ushort_t* Kbf  = (ushort_t*)(ws + 294912);    // 2048*256 bf16
    ushort_t* Vt   = (ushort_t*)(ws + 557056);    // [256][2048] bf16, pi-permuted
    ushort_t* AObf = (ushort_t*)(ws + 819200);    // 2048*256 bf16

    k_proj2rope<<<dim3(32, 8), 256, 0, stream>>>(x, Wq, Wk, Qrot, Kbf, Vt, psum);
    k_attn<<<dim3(64, 8), 256, 0, stream>>>(tp, Qrot, Kbf, Vt, psum, AObf);
    k_proj1<<<dim3(32, 8), 256, 0, stream>>>(AObf, Wo, out);
}